// Round 1
// baseline (24110.649 us; speedup 1.0000x reference)
//
#include <hip/hip_runtime.h>
#include <cstdint>

#define BATCH 64
#define SEQ   1024
#define FEAT  16
#define HID   256
#define GATE  768   // 3*HID
#define TC    256   // time-chunk length

__device__ __forceinline__ float sigmoidf_(float x) { return 1.0f / (1.0f + expf(-x)); }

// ---------------------------------------------------------------------------
// Layer-0 input projection: xp[r, col] = b0[col] + sum_f float(batch[b,t,f]) * W0[f,col]
// r = chunk-local row (b*TC + tl), t = t0 + tl
// ---------------------------------------------------------------------------
__global__ __launch_bounds__(256) void k_xp0(
    const int* __restrict__ batch, const float* __restrict__ W0,
    const float* __restrict__ b0, float* __restrict__ xp, int t0)
{
    const int r   = blockIdx.x;                 // 0 .. BATCH*TC-1
    const int col = blockIdx.y * 256 + threadIdx.x;   // 0 .. GATE-1
    const int b   = r >> 8;                     // TC == 256
    const int tl  = r & (TC - 1);
    const int* x = batch + ((size_t)b * SEQ + t0 + tl) * FEAT;
    float acc = b0[col];
#pragma unroll
    for (int f = 0; f < FEAT; ++f)
        acc += (float)x[f] * W0[f * GATE + col];
    xp[(size_t)r * GATE + col] = acc;
}

// ---------------------------------------------------------------------------
// Layers 1/2 input projection GEMM: xp[r, n] = b0row[n] + sum_k Y[b, t0+tl, k] * W[k, n]
// Tile: 64(M) x 128(N), K-step 16. 256 threads, 8x4 micro-tile per thread.
// ---------------------------------------------------------------------------
#define BM 64
#define BN 128
#define BK 16

__global__ __launch_bounds__(256) void k_gemm(
    const float* __restrict__ Y, const float* __restrict__ W,
    const float* __restrict__ b0, float* __restrict__ xp, int t0)
{
    __shared__ float As[BK][BM + 4];   // A transposed: As[k][m]
    __shared__ float Bs[BK][BN];

    const int m0 = blockIdx.x * BM;
    const int n0 = blockIdx.y * BN;
    const int tid = threadIdx.x;
    const int tx = tid & 31;          // 32 col groups * 4 cols
    const int ty = tid >> 5;          // 8 row groups * 8 rows
    const int ar = tid >> 2;          // A-load row 0..63
    const int ac = (tid & 3) * 4;     // A-load col-of-4
    const int kr = tid >> 4;          // B-load row 0..15
    const int bc = (tid & 15) * 8;    // B-load col-of-8

    float acc[8][4] = {};

    for (int k0 = 0; k0 < HID; k0 += BK) {
        {
            const int r  = m0 + ar;
            const int b  = r >> 8;
            const int tl = r & (TC - 1);
            float4 av = *(const float4*)(Y + ((size_t)b * SEQ + t0 + tl) * HID + k0 + ac);
            As[ac + 0][ar] = av.x; As[ac + 1][ar] = av.y;
            As[ac + 2][ar] = av.z; As[ac + 3][ar] = av.w;
            float4 bv0 = *(const float4*)(W + (size_t)(k0 + kr) * GATE + n0 + bc);
            float4 bv1 = *(const float4*)(W + (size_t)(k0 + kr) * GATE + n0 + bc + 4);
            *(float4*)&Bs[kr][bc]     = bv0;
            *(float4*)&Bs[kr][bc + 4] = bv1;
        }
        __syncthreads();
#pragma unroll
        for (int k = 0; k < BK; ++k) {
            float4 a0 = *(const float4*)&As[k][ty * 8];
            float4 a1 = *(const float4*)&As[k][ty * 8 + 4];
            float4 bv = *(const float4*)&Bs[k][tx * 4];
            float av_[8] = {a0.x, a0.y, a0.z, a0.w, a1.x, a1.y, a1.z, a1.w};
            float bv_[4] = {bv.x, bv.y, bv.z, bv.w};
#pragma unroll
            for (int i = 0; i < 8; ++i)
#pragma unroll
                for (int j = 0; j < 4; ++j)
                    acc[i][j] += av_[i] * bv_[j];
        }
        __syncthreads();
    }

#pragma unroll
    for (int i = 0; i < 8; ++i) {
        const int r = m0 + ty * 8 + i;
        float* crow = xp + (size_t)r * GATE + n0 + tx * 4;
#pragma unroll
        for (int j = 0; j < 4; ++j)
            crow[j] = acc[i][j] + b0[n0 + tx * 4 + j];
    }
}

// ---------------------------------------------------------------------------
// GRU recurrence over one time chunk. One block per batch element.
// 768 threads: thread g computes rec[g] = b1[g] + sum_k h[k]*U[k,g];
// threads g<256 then do gates and the state update (Keras reset_after).
// ---------------------------------------------------------------------------
__global__ __launch_bounds__(GATE) void k_gru(
    const float* __restrict__ xp, const float* __restrict__ U,
    const float* __restrict__ b1, const int* __restrict__ batch,
    float* __restrict__ out, float* __restrict__ hfinal,
    float* __restrict__ hstate, int t0)
{
    __shared__ float hs[HID];
    __shared__ float rec[GATE];

    const int b = blockIdx.x;
    const int g = threadIdx.x;

    if (g < HID) hs[g] = (t0 == 0) ? 0.0f : hstate[b * HID + g];
    const float bg = b1[g];
    const float* __restrict__ Ucol = U + g;
    const float4* h4 = (const float4*)hs;
    __syncthreads();

    for (int tl = 0; tl < TC; ++tl) {
        const int t = t0 + tl;
        float acc = bg;
#pragma unroll 8
        for (int kk = 0; kk < HID / 4; ++kk) {
            float4 hv = h4[kk];
            acc += hv.x * Ucol[(size_t)(4 * kk + 0) * GATE];
            acc += hv.y * Ucol[(size_t)(4 * kk + 1) * GATE];
            acc += hv.z * Ucol[(size_t)(4 * kk + 2) * GATE];
            acc += hv.w * Ucol[(size_t)(4 * kk + 3) * GATE];
        }
        rec[g] = acc;
        __syncthreads();

        if (g < HID) {
            const bool live = batch[((size_t)b * SEQ + t) * FEAT + (FEAT - 1)] != -1;
            const float* xr = xp + ((size_t)b * TC + tl) * GATE;
            float z  = sigmoidf_(xr[g] + rec[g]);
            float r  = sigmoidf_(xr[HID + g] + rec[HID + g]);
            float hh = tanhf(xr[2 * HID + g] + r * rec[2 * HID + g]);
            float hp = hs[g];
            float hn = z * hp + (1.0f - z) * hh;
            hn = live ? hn : hp;
            hs[g] = hn;
            out[((size_t)b * SEQ + t) * HID + g] = hn;
        }
        __syncthreads();
    }

    if (g < HID) {
        hstate[b * HID + g] = hs[g];
        if (hfinal) hfinal[b * HID + g] = hs[g];
    }
}

// ---------------------------------------------------------------------------
extern "C" void kernel_launch(void* const* d_in, const int* in_sizes, int n_in,
                              void* d_out, int out_size, void* d_ws, size_t ws_size,
                              hipStream_t stream)
{
    const int*   batch = (const int*)d_in[0];
    const float* W0 = (const float*)d_in[1];
    const float* U0 = (const float*)d_in[2];
    const float* b0 = (const float*)d_in[3];
    const float* W1 = (const float*)d_in[4];
    const float* U1 = (const float*)d_in[5];
    const float* b1 = (const float*)d_in[6];
    const float* W2 = (const float*)d_in[7];
    const float* U2 = (const float*)d_in[8];
    const float* b2 = (const float*)d_in[9];

    float* out  = (float*)d_out;
    float* hfin = out + (size_t)BATCH * SEQ * HID;

    // workspace layout: xp chunk [BATCH*TC*GATE] | y [BATCH*SEQ*HID] | hstate [BATCH*HID]
    float* xp = (float*)d_ws;
    float* y  = (float*)((char*)d_ws + (size_t)BATCH * TC * GATE * 4);
    float* hstate = (float*)((char*)d_ws + (size_t)BATCH * TC * GATE * 4
                                         + (size_t)BATCH * SEQ * HID * 4);

    dim3 gxp0(BATCH * TC, 3), bxp0(256);
    dim3 ggemm(BATCH * TC / BM, GATE / BN), bgemm(256);
    dim3 ggru(BATCH), bgru(GATE);

    // ----- layer 0 -----
    for (int t0 = 0; t0 < SEQ; t0 += TC) {
        k_xp0<<<gxp0, bxp0, 0, stream>>>(batch, W0, b0, xp, t0);
        k_gru<<<ggru, bgru, 0, stream>>>(xp, U0, b0 + GATE, batch, y, nullptr, hstate, t0);
    }
    // ----- layer 1 -----
    for (int t0 = 0; t0 < SEQ; t0 += TC) {
        k_gemm<<<ggemm, bgemm, 0, stream>>>(y, W1, b1, xp, t0);
        k_gru<<<ggru, bgru, 0, stream>>>(xp, U1, b1 + GATE, batch, y, nullptr, hstate, t0);
    }
    // ----- layer 2 -----
    for (int t0 = 0; t0 < SEQ; t0 += TC) {
        k_gemm<<<ggemm, bgemm, 0, stream>>>(y, W2, b2, xp, t0);
        k_gru<<<ggru, bgru, 0, stream>>>(xp, U2, b2 + GATE, batch, out,
                                         (t0 + TC == SEQ) ? hfin : nullptr, hstate, t0);
    }
}

// Round 2
// 4695.074 us; speedup vs baseline: 5.1353x; 5.1353x over previous
//
#include <hip/hip_runtime.h>
#include <cstdint>

#define BATCH 64
#define SEQ   1024
#define FEAT  16
#define HID   256
#define GATE  768   // 3*HID
#define TC    128   // time-chunk length
#define TCSH  7     // log2(TC)

typedef _Float16 h2 __attribute__((ext_vector_type(2)));

__device__ __forceinline__ float dot2f(float a, float b, float c) {
    return __builtin_amdgcn_fdot2(__builtin_bit_cast(h2, a),
                                  __builtin_bit_cast(h2, b), c, false);
}
__device__ __forceinline__ float sigmoidf_(float x) { return 1.0f / (1.0f + __expf(-x)); }
__device__ __forceinline__ float tanhf_(float x)    { return 2.0f / (1.0f + __expf(-2.0f * x)) - 1.0f; }

// ---------------------------------------------------------------------------
// Pack U (fp32 [HID][GATE]) -> Upk (f16x2 as float dwords, [GATE][HID/2]):
// Upk[c][kk] = (half(U[2kk][c]), half(U[2kk+1][c]))
// ---------------------------------------------------------------------------
__global__ __launch_bounds__(256) void k_packU(const float* __restrict__ U,
                                               float* __restrict__ Upk)
{
    const int idx = blockIdx.x * 256 + threadIdx.x;   // < GATE * 128
    const int c  = idx >> 7;
    const int kk = idx & 127;
    h2 v;
    v.x = (_Float16)U[(size_t)(2 * kk)     * GATE + c];
    v.y = (_Float16)U[(size_t)(2 * kk + 1) * GATE + c];
    Upk[idx] = __builtin_bit_cast(float, v);
}

// ---------------------------------------------------------------------------
// Layer-0 input projection
// ---------------------------------------------------------------------------
__global__ __launch_bounds__(256) void k_xp0(
    const int* __restrict__ batch, const float* __restrict__ W0,
    const float* __restrict__ b0, float* __restrict__ xp, int t0)
{
    const int r   = blockIdx.x;                       // 0 .. BATCH*TC-1
    const int col = blockIdx.y * 256 + threadIdx.x;   // 0 .. GATE-1
    const int b   = r >> TCSH;
    const int tl  = r & (TC - 1);
    const int* x = batch + ((size_t)b * SEQ + t0 + tl) * FEAT;
    float acc = b0[col];
#pragma unroll
    for (int f = 0; f < FEAT; ++f)
        acc += (float)x[f] * W0[f * GATE + col];
    xp[(size_t)r * GATE + col] = acc;
}

// ---------------------------------------------------------------------------
// Layers 1/2 input projection GEMM (64x128 tile, K-step 16)
// ---------------------------------------------------------------------------
#define BM 64
#define BN 128
#define BK 16

__global__ __launch_bounds__(256) void k_gemm(
    const float* __restrict__ Y, const float* __restrict__ W,
    const float* __restrict__ b0, float* __restrict__ xp, int t0)
{
    __shared__ float As[BK][BM + 4];
    __shared__ float Bs[BK][BN];

    const int m0 = blockIdx.x * BM;
    const int n0 = blockIdx.y * BN;
    const int tid = threadIdx.x;
    const int tx = tid & 31;
    const int ty = tid >> 5;
    const int ar = tid >> 2;
    const int ac = (tid & 3) * 4;
    const int kr = tid >> 4;
    const int bc = (tid & 15) * 8;

    float acc[8][4] = {};

    for (int k0 = 0; k0 < HID; k0 += BK) {
        {
            const int r  = m0 + ar;
            const int b  = r >> TCSH;
            const int tl = r & (TC - 1);
            float4 av = *(const float4*)(Y + ((size_t)b * SEQ + t0 + tl) * HID + k0 + ac);
            As[ac + 0][ar] = av.x; As[ac + 1][ar] = av.y;
            As[ac + 2][ar] = av.z; As[ac + 3][ar] = av.w;
            float4 bv0 = *(const float4*)(W + (size_t)(k0 + kr) * GATE + n0 + bc);
            float4 bv1 = *(const float4*)(W + (size_t)(k0 + kr) * GATE + n0 + bc + 4);
            *(float4*)&Bs[kr][bc]     = bv0;
            *(float4*)&Bs[kr][bc + 4] = bv1;
        }
        __syncthreads();
#pragma unroll
        for (int k = 0; k < BK; ++k) {
            float4 a0 = *(const float4*)&As[k][ty * 8];
            float4 a1 = *(const float4*)&As[k][ty * 8 + 4];
            float4 bv = *(const float4*)&Bs[k][tx * 4];
            float av_[8] = {a0.x, a0.y, a0.z, a0.w, a1.x, a1.y, a1.z, a1.w};
            float bv_[4] = {bv.x, bv.y, bv.z, bv.w};
#pragma unroll
            for (int i = 0; i < 8; ++i)
#pragma unroll
                for (int j = 0; j < 4; ++j)
                    acc[i][j] += av_[i] * bv_[j];
        }
        __syncthreads();
    }

#pragma unroll
    for (int i = 0; i < 8; ++i) {
        const int r = m0 + ty * 8 + i;
        float* crow = xp + (size_t)r * GATE + n0 + tx * 4;
#pragma unroll
        for (int j = 0; j < 4; ++j)
            crow[j] = acc[i][j] + b0[n0 + tx * 4 + j];
    }
}

// ---------------------------------------------------------------------------
// GRU recurrence, register-resident f16 U.
// 768 threads; thread t owns gate-column pair {t&~1, t|1} for k-half j=t&1.
// Per step: 16 broadcast ds_read_b128 of f16-packed h + 128 v_dot2_f32_f16,
// shfl_xor(1) reduce, gate math on threads < 256.
// ---------------------------------------------------------------------------
__global__ __launch_bounds__(GATE) void k_gru(
    const float* __restrict__ xp, const float* __restrict__ Upk,
    const float* __restrict__ b1, const int* __restrict__ batch,
    float* __restrict__ out, float* __restrict__ hfinal,
    float* __restrict__ hstate, int t0)
{
    __shared__ __align__(16) float hs2[HID / 2];   // h packed as f16 pairs
    __shared__ float rec[GATE];

    const int b  = blockIdx.x;
    const int t_ = threadIdx.x;
    const int c0 = t_ & ~1;
    const int j  = t_ & 1;

    // ---- load U fragment into registers: 2 columns x 64 f16-pair dwords ----
    float u0r[64], u1r[64];
    {
        const float4* s0 = (const float4*)(Upk + (size_t)c0 * 128 + 64 * j);
        const float4* s1 = (const float4*)(Upk + (size_t)(c0 + 1) * 128 + 64 * j);
#pragma unroll
        for (int i = 0; i < 16; ++i) {
            float4 a = s0[i];
            u0r[4 * i + 0] = a.x; u0r[4 * i + 1] = a.y;
            u0r[4 * i + 2] = a.z; u0r[4 * i + 3] = a.w;
            float4 bb = s1[i];
            u1r[4 * i + 0] = bb.x; u1r[4 * i + 1] = bb.y;
            u1r[4 * i + 2] = bb.z; u1r[4 * i + 3] = bb.w;
        }
    }

    const float bias0 = (j == 0) ? b1[c0]     : 0.0f;
    const float bias1 = (j == 0) ? b1[c0 + 1] : 0.0f;

    // ---- init h ----
    float hprev = 0.0f;
    if (t_ < HID) {
        hprev = (t0 == 0) ? 0.0f : hstate[b * HID + t_];
        ((_Float16*)hs2)[t_] = (_Float16)hprev;
    }
    __syncthreads();

    const float4* h4 = ((const float4*)hs2) + 16 * j;

    for (int tl = 0; tl < TC; ++tl) {
        const int t = t0 + tl;

        // prefetch xp row + mask (independent of h; hides L2 latency under matvec)
        float xz = 0.f, xr = 0.f, xh = 0.f;
        int mflag = 0;
        if (t_ < HID) {
            const float* xrow = xp + ((size_t)b * TC + tl) * GATE;
            xz = xrow[t_];
            xr = xrow[HID + t_];
            xh = xrow[2 * HID + t_];
            mflag = batch[((size_t)b * SEQ + t) * FEAT + (FEAT - 1)];
        }

        // ---- matvec: rec = h @ U + b1 ----
        float acc0 = bias0, acc1 = bias1;
#pragma unroll
        for (int i = 0; i < 16; ++i) {
            float4 hv = h4[i];
            acc0 = dot2f(hv.x, u0r[4 * i + 0], acc0);
            acc0 = dot2f(hv.y, u0r[4 * i + 1], acc0);
            acc0 = dot2f(hv.z, u0r[4 * i + 2], acc0);
            acc0 = dot2f(hv.w, u0r[4 * i + 3], acc0);
            acc1 = dot2f(hv.x, u1r[4 * i + 0], acc1);
            acc1 = dot2f(hv.y, u1r[4 * i + 1], acc1);
            acc1 = dot2f(hv.z, u1r[4 * i + 2], acc1);
            acc1 = dot2f(hv.w, u1r[4 * i + 3], acc1);
        }
        acc0 += __shfl_xor(acc0, 1, 64);
        acc1 += __shfl_xor(acc1, 1, 64);
        rec[t_] = j ? acc1 : acc0;
        __syncthreads();

        // ---- gates + state update (Keras reset_after) ----
        if (t_ < HID) {
            float z  = sigmoidf_(xz + rec[t_]);
            float r  = sigmoidf_(xr + rec[HID + t_]);
            float hh = tanhf_(xh + r * rec[2 * HID + t_]);
            float hn = z * hprev + (1.0f - z) * hh;
            hn = (mflag != -1) ? hn : hprev;
            hprev = hn;
            out[((size_t)b * SEQ + t) * HID + t_] = hn;
            ((_Float16*)hs2)[t_] = (_Float16)hn;
        }
        __syncthreads();
    }

    if (t_ < HID) {
        hstate[b * HID + t_] = hprev;
        if (hfinal) hfinal[b * HID + t_] = hprev;
    }
}

// ---------------------------------------------------------------------------
extern "C" void kernel_launch(void* const* d_in, const int* in_sizes, int n_in,
                              void* d_out, int out_size, void* d_ws, size_t ws_size,
                              hipStream_t stream)
{
    const int*   batch = (const int*)d_in[0];
    const float* W0 = (const float*)d_in[1];
    const float* U0 = (const float*)d_in[2];
    const float* b0 = (const float*)d_in[3];
    const float* W1 = (const float*)d_in[4];
    const float* U1 = (const float*)d_in[5];
    const float* b1 = (const float*)d_in[6];
    const float* W2 = (const float*)d_in[7];
    const float* U2 = (const float*)d_in[8];
    const float* b2 = (const float*)d_in[9];

    float* out  = (float*)d_out;
    float* hfin = out + (size_t)BATCH * SEQ * HID;

    // ws layout: xp chunk | y | hstate | Upk0 | Upk1 | Upk2
    float* xp     = (float*)d_ws;
    float* y      = xp + (size_t)BATCH * TC * GATE;
    float* hstate = y + (size_t)BATCH * SEQ * HID;
    float* Upk0   = hstate + (size_t)BATCH * HID;
    float* Upk1   = Upk0 + (size_t)GATE * 128;
    float* Upk2   = Upk1 + (size_t)GATE * 128;

    dim3 gpack(GATE * 128 / 256), bpack(256);
    dim3 gxp0(BATCH * TC, 3), bxp0(256);
    dim3 ggemm(BATCH * TC / BM, GATE / BN), bgemm(256);
    dim3 ggru(BATCH), bgru(GATE);

    k_packU<<<gpack, bpack, 0, stream>>>(U0, Upk0);
    k_packU<<<gpack, bpack, 0, stream>>>(U1, Upk1);
    k_packU<<<gpack, bpack, 0, stream>>>(U2, Upk2);

    // ----- layer 0 -----
    for (int t0 = 0; t0 < SEQ; t0 += TC) {
        k_xp0<<<gxp0, bxp0, 0, stream>>>(batch, W0, b0, xp, t0);
        k_gru<<<ggru, bgru, 0, stream>>>(xp, Upk0, b0 + GATE, batch, y, nullptr, hstate, t0);
    }
    // ----- layer 1 -----
    for (int t0 = 0; t0 < SEQ; t0 += TC) {
        k_gemm<<<ggemm, bgemm, 0, stream>>>(y, W1, b1, xp, t0);
        k_gru<<<ggru, bgru, 0, stream>>>(xp, Upk1, b1 + GATE, batch, y, nullptr, hstate, t0);
    }
    // ----- layer 2 -----
    for (int t0 = 0; t0 < SEQ; t0 += TC) {
        k_gemm<<<ggemm, bgemm, 0, stream>>>(y, W2, b2, xp, t0);
        k_gru<<<ggru, bgru, 0, stream>>>(xp, Upk2, b2 + GATE, batch, out,
                                         (t0 + TC == SEQ) ? hfin : nullptr, hstate, t0);
    }
}